// Round 2
// baseline (644.939 us; speedup 1.0000x reference)
//
#include <hip/hip_runtime.h>

#define N_NODES  50000
#define N_EDGES  1200000
#define N_GRAPHS 1024
#define N_FEAT   9
#define EMB      64

// ---------------------------------------------------------------------------
// CSR build: histogram of dst -> exclusive scan -> scatter fill
// ---------------------------------------------------------------------------

__global__ __launch_bounds__(256) void count_kernel(const int* __restrict__ dst,
                                                    int* __restrict__ cnt, int ne) {
    int i = blockIdx.x * blockDim.x + threadIdx.x;
    if (i < ne) atomicAdd(&cnt[dst[i]], 1);
}

__global__ __launch_bounds__(256) void deg_kernel(const int* __restrict__ cnt,
                                                  float* __restrict__ dinv,
                                                  float* __restrict__ selfn, int n) {
    int i = blockIdx.x * blockDim.x + threadIdx.x;
    if (i >= n) return;
    float d = (float)cnt[i] + 1.0f;      // degree with self-loop
    dinv[i]  = rsqrtf(d);
    selfn[i] = 1.0f / d;
}

// single-block exclusive scan of 50000 counts (1024 threads, ~49 elems each)
__global__ __launch_bounds__(1024) void scan_kernel(const int* __restrict__ cnt,
                                                    int* __restrict__ rowp, int n) {
    __shared__ int part[1024];
    int t = threadIdx.x;
    const int CH = (n + 1023) / 1024;
    int lo = t * CH, hi = min(lo + CH, n);
    int s = 0;
    for (int i = lo; i < hi; ++i) s += cnt[i];
    part[t] = s;
    __syncthreads();
    for (int off = 1; off < 1024; off <<= 1) {
        int v = (t >= off) ? part[t - off] : 0;
        __syncthreads();
        part[t] += v;
        __syncthreads();
    }
    int base = (t == 0) ? 0 : part[t - 1];
    for (int i = lo; i < hi; ++i) { rowp[i] = base; base += cnt[i]; }
    if (t == 1023) rowp[n] = base;   // == total edges
}

__global__ __launch_bounds__(256) void fill_kernel(const int* __restrict__ src,
                                                   const int* __restrict__ dst,
                                                   const float* __restrict__ dinv,
                                                   const int* __restrict__ rowp,
                                                   int* __restrict__ fill,
                                                   int2* __restrict__ csr, int ne) {
    int i = blockIdx.x * blockDim.x + threadIdx.x;
    if (i >= ne) return;
    int s = src[i], d = dst[i];
    float norm = dinv[s] * dinv[d];
    int pos = rowp[d] + atomicAdd(&fill[d], 1);
    csr[pos] = make_int2(s, __float_as_int(norm));
}

__global__ __launch_bounds__(256) void boundary_kernel(const int* __restrict__ batch,
                                                       int* __restrict__ gstart,
                                                       int n, int ngraphs) {
    int i = blockIdx.x * blockDim.x + threadIdx.x;
    if (i >= n) return;
    int b = batch[i];
    if (i == 0 || batch[i - 1] != b) gstart[b] = i;
    if (i == 0) gstart[ngraphs] = n;
}

// ---------------------------------------------------------------------------
// Layer-0 aggregation on raw 9-dim features: a[i] = sum_e norm_e*x[src] + selfn_i*x[i]
// wave per node; lane = 9*slot + feat; 7 edges per iteration (lanes 0..62)
// ---------------------------------------------------------------------------

__global__ __launch_bounds__(256) void agg9_kernel(const float* __restrict__ x,
                                                   const int2* __restrict__ csr,
                                                   const int* __restrict__ rowp,
                                                   const float* __restrict__ selfn,
                                                   float* __restrict__ a, int n) {
    int wave = blockIdx.x * (blockDim.x >> 6) + (threadIdx.x >> 6);
    int lane = threadIdx.x & 63;
    if (wave >= n) return;
    int beg = rowp[wave], end = rowp[wave + 1];
    int slot = lane / 9;          // 0..7 (lane 63 -> slot 7, masked)
    int f    = lane - slot * 9;   // 0..8
    float p = 0.0f;
    int e = beg;
    for (; e + 7 <= end; e += 7) {
        if (slot < 7) {
            int2 c = csr[e + slot];
            p += __int_as_float(c.y) * x[c.x * N_FEAT + f];
        }
    }
    for (; e < end; ++e) {
        if (lane < N_FEAT) {
            int2 c = csr[e];
            p += __int_as_float(c.y) * x[c.x * N_FEAT + lane];
        }
    }
    // reduce slots 1..6 into lanes 0..8 (slot-0 partial already includes tail)
    float tot = p;
#pragma unroll
    for (int s = 1; s < 7; ++s) {
        float t = __shfl(p, 9 * s + lane, 64);
        if (lane < N_FEAT) tot += t;
    }
    if (lane < N_FEAT)
        a[wave * N_FEAT + lane] = tot + selfn[wave] * x[wave * N_FEAT + lane];
}

// ---------------------------------------------------------------------------
// 64-dim aggregation: a[i] = sum_e norm_e * h[src] + selfn_i * h[i]
// wave per node, lane per feature, register accumulate, 4x unrolled gathers
// ---------------------------------------------------------------------------

__global__ __launch_bounds__(256) void agg64_kernel(const float* __restrict__ h,
                                                    const int2* __restrict__ csr,
                                                    const int* __restrict__ rowp,
                                                    const float* __restrict__ selfn,
                                                    float* __restrict__ a, int n) {
    int wave = blockIdx.x * (blockDim.x >> 6) + (threadIdx.x >> 6);
    int lane = threadIdx.x & 63;
    if (wave >= n) return;
    int beg = rowp[wave], end = rowp[wave + 1];
    float acc = selfn[wave] * h[wave * EMB + lane];
    int e = beg;
    for (; e + 4 <= end; e += 4) {
        int2 c0 = csr[e], c1 = csr[e + 1], c2 = csr[e + 2], c3 = csr[e + 3];
        float v0 = h[c0.x * EMB + lane];
        float v1 = h[c1.x * EMB + lane];
        float v2 = h[c2.x * EMB + lane];
        float v3 = h[c3.x * EMB + lane];
        acc += __int_as_float(c0.y) * v0 + __int_as_float(c1.y) * v1 +
               __int_as_float(c2.y) * v2 + __int_as_float(c3.y) * v3;
    }
    for (; e < end; ++e) {
        int2 c = csr[e];
        acc += __int_as_float(c.y) * h[c.x * EMB + lane];
    }
    a[wave * EMB + lane] = acc;
}

// ---------------------------------------------------------------------------
// Dense GEMV + bias + tanh: out[i,:] = tanh(in[i,:K] @ W[K,64] + b)
// wave per node, lane per output feature, W staged in LDS
// ---------------------------------------------------------------------------

template <int K>
__global__ __launch_bounds__(256) void gemv_kernel(const float* __restrict__ in,
                                                   const float* __restrict__ W,
                                                   const float* __restrict__ b,
                                                   float* __restrict__ out, int n) {
    __shared__ float sW[K * EMB];
    for (int i = threadIdx.x; i < K * EMB; i += blockDim.x) sW[i] = W[i];
    __syncthreads();
    int wave = blockIdx.x * (blockDim.x >> 6) + (threadIdx.x >> 6);
    int lane = threadIdx.x & 63;
    if (wave >= n) return;
    float v = (lane < K) ? in[wave * K + lane] : 0.0f;
    float acc = b[lane];
#pragma unroll
    for (int k = 0; k < K; ++k) {
        float hk = __shfl(v, k, 64);
        acc = fmaf(hk, sW[k * EMB + lane], acc);
    }
    out[wave * EMB + lane] = tanhf(acc);
}

// ---------------------------------------------------------------------------
// Fused pooling (segment max + mean) + output GEMV: one block (4 waves) per graph
// ---------------------------------------------------------------------------

__global__ __launch_bounds__(256) void pool_kernel(const float* __restrict__ h,
                                                   const int* __restrict__ gstart,
                                                   const float* __restrict__ Wout,
                                                   const float* __restrict__ bout,
                                                   float* __restrict__ out, int ng) {
    __shared__ float smx[4][EMB];
    __shared__ float ssm[4][EMB];
    int g = blockIdx.x;
    if (g >= ng) return;
    int w = threadIdx.x >> 6, lane = threadIdx.x & 63;
    int beg = gstart[g], end = gstart[g + 1];
    float mx = -3.0e38f, sm = 0.0f;
    for (int i = beg + w; i < end; i += 4) {
        float v = h[i * EMB + lane];
        mx = fmaxf(mx, v);
        sm += v;
    }
    smx[w][lane] = mx;
    ssm[w][lane] = sm;
    __syncthreads();
    if (w == 0) {
        mx = fmaxf(fmaxf(smx[0][lane], smx[1][lane]), fmaxf(smx[2][lane], smx[3][lane]));
        sm = ssm[0][lane] + ssm[1][lane] + ssm[2][lane] + ssm[3][lane];
        float mean = sm / (float)(end - beg);
        float r = mx * Wout[lane] + mean * Wout[EMB + lane];
#pragma unroll
        for (int off = 32; off; off >>= 1) r += __shfl_down(r, off, 64);
        if (lane == 0) out[g] = r + bout[0];
    }
}

// ---------------------------------------------------------------------------

extern "C" void kernel_launch(void* const* d_in, const int* in_sizes, int n_in,
                              void* d_out, int out_size, void* d_ws, size_t ws_size,
                              hipStream_t stream) {
    const float* x     = (const float*)d_in[0];
    const int*   ei    = (const int*)d_in[1];
    const int*   batch = (const int*)d_in[2];
    const float* W0 = (const float*)d_in[3];
    const float* b0 = (const float*)d_in[4];
    const float* W1 = (const float*)d_in[5];
    const float* b1 = (const float*)d_in[6];
    const float* W2 = (const float*)d_in[7];
    const float* b2 = (const float*)d_in[8];
    const float* W3 = (const float*)d_in[9];
    const float* b3 = (const float*)d_in[10];
    const float* Wout = (const float*)d_in[11];
    const float* bout = (const float*)d_in[12];
    float* out = (float*)d_out;

    // workspace layout (~36.4 MB)
    char* ws = (char*)d_ws;
    float* h_buf = (float*)ws;  ws += (size_t)N_NODES * EMB * 4;
    float* a_buf = (float*)ws;  ws += (size_t)N_NODES * EMB * 4;   // a9 aliases head
    int2*  csr   = (int2*)ws;   ws += (size_t)N_EDGES * 8;
    int*   cnt   = (int*)ws;    ws += (size_t)N_NODES * 4;
    int*   fill  = (int*)ws;    ws += (size_t)N_NODES * 4;   // contiguous after cnt
    int*   rowp  = (int*)ws;    ws += (size_t)(N_NODES + 1) * 4;
    float* dinv  = (float*)ws;  ws += (size_t)N_NODES * 4;
    float* selfn = (float*)ws;  ws += (size_t)N_NODES * 4;
    int*   gstart= (int*)ws;    ws += (size_t)(N_GRAPHS + 1) * 4;

    const int* srcp = ei;
    const int* dstp = ei + N_EDGES;

    // zero cnt+fill (contiguous; ws is re-poisoned 0xAA before every call)
    hipMemsetAsync(cnt, 0, (size_t)2 * N_NODES * 4, stream);

    int ebl = (N_EDGES + 255) / 256;
    int nbl = (N_NODES + 255) / 256;
    count_kernel<<<ebl, 256, 0, stream>>>(dstp, cnt, N_EDGES);
    deg_kernel<<<nbl, 256, 0, stream>>>(cnt, dinv, selfn, N_NODES);
    scan_kernel<<<1, 1024, 0, stream>>>(cnt, rowp, N_NODES);
    fill_kernel<<<ebl, 256, 0, stream>>>(srcp, dstp, dinv, rowp, fill, csr, N_EDGES);
    boundary_kernel<<<nbl, 256, 0, stream>>>(batch, gstart, N_NODES, N_GRAPHS);

    int wbl = (N_NODES + 3) / 4;  // 4 waves (nodes) per 256-thread block

    // layer 0: aggregate 9-dim x, then 9->64 GEMV (+bias+tanh)
    agg9_kernel<<<wbl, 256, 0, stream>>>(x, csr, rowp, selfn, a_buf, N_NODES);
    gemv_kernel<N_FEAT><<<wbl, 256, 0, stream>>>(a_buf, W0, b0, h_buf, N_NODES);

    // layers 1..3: aggregate 64-dim h, then 64->64 GEMV (+bias+tanh)
    agg64_kernel<<<wbl, 256, 0, stream>>>(h_buf, csr, rowp, selfn, a_buf, N_NODES);
    gemv_kernel<EMB><<<wbl, 256, 0, stream>>>(a_buf, W1, b1, h_buf, N_NODES);
    agg64_kernel<<<wbl, 256, 0, stream>>>(h_buf, csr, rowp, selfn, a_buf, N_NODES);
    gemv_kernel<EMB><<<wbl, 256, 0, stream>>>(a_buf, W2, b2, h_buf, N_NODES);
    agg64_kernel<<<wbl, 256, 0, stream>>>(h_buf, csr, rowp, selfn, a_buf, N_NODES);
    gemv_kernel<EMB><<<wbl, 256, 0, stream>>>(a_buf, W3, b3, h_buf, N_NODES);

    pool_kernel<<<N_GRAPHS, 256, 0, stream>>>(h_buf, gstart, Wout, bout, out, N_GRAPHS);
}

// Round 3
// 567.899 us; speedup vs baseline: 1.1357x; 1.1357x over previous
//
#include <hip/hip_runtime.h>

#define N_NODES  50000
#define N_EDGES  1200000
#define N_GRAPHS 1024
#define N_FEAT   9
#define EMB      64
#define SCAN_NB  ((N_NODES + 255) / 256)   // 196 blocks

// ---------------------------------------------------------------------------
// CSR build: histogram of dst -> two-kernel multiblock scan -> scatter fill
// ---------------------------------------------------------------------------

__global__ __launch_bounds__(256) void count_kernel(const int* __restrict__ dst,
                                                    int* __restrict__ cnt, int ne) {
    int i = blockIdx.x * blockDim.x + threadIdx.x;
    if (i < ne) atomicAdd(&cnt[dst[i]], 1);
}

// per-block sums of cnt (for the scan) + degree-derived node scalars
__global__ __launch_bounds__(256) void blocksum_kernel(const int* __restrict__ cnt,
                                                       int* __restrict__ bsum,
                                                       float* __restrict__ dinv,
                                                       float* __restrict__ selfn,
                                                       int n) {
    __shared__ int sw[4];
    int t = threadIdx.x;
    int i = blockIdx.x * 256 + t;
    int v = (i < n) ? cnt[i] : 0;
    if (i < n) {
        float d = (float)v + 1.0f;       // degree with self-loop
        dinv[i]  = rsqrtf(d);
        selfn[i] = 1.0f / d;
    }
    int r = v;
#pragma unroll
    for (int off = 32; off; off >>= 1) r += __shfl_down(r, off, 64);
    if ((t & 63) == 0) sw[t >> 6] = r;
    __syncthreads();
    if (t == 0) bsum[blockIdx.x] = sw[0] + sw[1] + sw[2] + sw[3];
}

// block prefix from bsum + block-local exclusive scan -> rowp
__global__ __launch_bounds__(256) void scanfill_kernel(const int* __restrict__ cnt,
                                                       const int* __restrict__ bsum,
                                                       int* __restrict__ rowp, int n) {
    __shared__ int sw[4];
    __shared__ int s_off;
    __shared__ int lds[256];
    int t = threadIdx.x;
    // prefix over earlier blocks (<=196 values, one per lane)
    int p = (t < blockIdx.x) ? bsum[t] : 0;
#pragma unroll
    for (int off = 32; off; off >>= 1) p += __shfl_down(p, off, 64);
    if ((t & 63) == 0) sw[t >> 6] = p;
    __syncthreads();
    if (t == 0) s_off = sw[0] + sw[1] + sw[2] + sw[3];
    // block-local inclusive scan of 256 counts
    int i = blockIdx.x * 256 + t;
    int v = (i < n) ? cnt[i] : 0;
    lds[t] = v;
    __syncthreads();
    for (int off = 1; off < 256; off <<= 1) {
        int u = (t >= off) ? lds[t - off] : 0;
        __syncthreads();
        lds[t] += u;
        __syncthreads();
    }
    if (i < n) rowp[i] = s_off + lds[t] - v;   // exclusive
    if (i == 0) rowp[n] = N_EDGES;
}

__global__ __launch_bounds__(256) void fill_kernel(const int* __restrict__ src,
                                                   const int* __restrict__ dst,
                                                   const float* __restrict__ dinv,
                                                   const int* __restrict__ rowp,
                                                   int* __restrict__ fill,
                                                   int2* __restrict__ csr, int ne) {
    int i = blockIdx.x * blockDim.x + threadIdx.x;
    if (i >= ne) return;
    int s = src[i], d = dst[i];
    float norm = dinv[s] * dinv[d];
    int pos = rowp[d] + atomicAdd(&fill[d], 1);
    csr[pos] = make_int2(s, __float_as_int(norm));
}

__global__ __launch_bounds__(256) void boundary_kernel(const int* __restrict__ batch,
                                                       int* __restrict__ gstart,
                                                       int n, int ngraphs) {
    int i = blockIdx.x * blockDim.x + threadIdx.x;
    if (i >= n) return;
    int b = batch[i];
    if (i == 0 || batch[i - 1] != b) gstart[b] = i;
    if (i == 0) gstart[ngraphs] = n;
}

// ---------------------------------------------------------------------------
// Layer-0 aggregation on raw 9-dim features: a[i] = sum_e norm_e*x[src] + selfn_i*x[i]
// wave per node; lane = 9*slot + feat; 7 edges per iteration (lanes 0..62)
// ---------------------------------------------------------------------------

__global__ __launch_bounds__(256) void agg9_kernel(const float* __restrict__ x,
                                                   const int2* __restrict__ csr,
                                                   const int* __restrict__ rowp,
                                                   const float* __restrict__ selfn,
                                                   float* __restrict__ a, int n) {
    int wave = blockIdx.x * (blockDim.x >> 6) + (threadIdx.x >> 6);
    int lane = threadIdx.x & 63;
    if (wave >= n) return;
    int beg = rowp[wave], end = rowp[wave + 1];
    int slot = lane / 9;          // 0..7 (lane 63 -> slot 7, masked)
    int f    = lane - slot * 9;   // 0..8
    float p = 0.0f;
    int e = beg;
    for (; e + 7 <= end; e += 7) {
        if (slot < 7) {
            int2 c = csr[e + slot];
            p += __int_as_float(c.y) * x[c.x * N_FEAT + f];
        }
    }
    for (; e < end; ++e) {
        if (lane < N_FEAT) {
            int2 c = csr[e];
            p += __int_as_float(c.y) * x[c.x * N_FEAT + lane];
        }
    }
    float tot = p;
#pragma unroll
    for (int s = 1; s < 7; ++s) {
        float t = __shfl(p, 9 * s + lane, 64);
        if (lane < N_FEAT) tot += t;
    }
    if (lane < N_FEAT)
        a[wave * N_FEAT + lane] = tot + selfn[wave] * x[wave * N_FEAT + lane];
}

// ---------------------------------------------------------------------------
// 64-dim aggregation: a[i] = sum_e norm_e * h[src] + selfn_i * h[i]
// wave per node, lane per feature, register accumulate, 4x unrolled gathers
// ---------------------------------------------------------------------------

__global__ __launch_bounds__(256) void agg64_kernel(const float* __restrict__ h,
                                                    const int2* __restrict__ csr,
                                                    const int* __restrict__ rowp,
                                                    const float* __restrict__ selfn,
                                                    float* __restrict__ a, int n) {
    int wave = blockIdx.x * (blockDim.x >> 6) + (threadIdx.x >> 6);
    int lane = threadIdx.x & 63;
    if (wave >= n) return;
    int beg = rowp[wave], end = rowp[wave + 1];
    float acc = selfn[wave] * h[wave * EMB + lane];
    int e = beg;
    for (; e + 4 <= end; e += 4) {
        int2 c0 = csr[e], c1 = csr[e + 1], c2 = csr[e + 2], c3 = csr[e + 3];
        float v0 = h[c0.x * EMB + lane];
        float v1 = h[c1.x * EMB + lane];
        float v2 = h[c2.x * EMB + lane];
        float v3 = h[c3.x * EMB + lane];
        acc += __int_as_float(c0.y) * v0 + __int_as_float(c1.y) * v1 +
               __int_as_float(c2.y) * v2 + __int_as_float(c3.y) * v3;
    }
    for (; e < end; ++e) {
        int2 c = csr[e];
        acc += __int_as_float(c.y) * h[c.x * EMB + lane];
    }
    a[wave * EMB + lane] = acc;
}

// ---------------------------------------------------------------------------
// Dense GEMV + bias + tanh: out[i,:] = tanh(in[i,:K] @ W[K,64] + b)
// wave per node, lane per output feature, W staged in LDS
// ---------------------------------------------------------------------------

template <int K>
__global__ __launch_bounds__(256) void gemv_kernel(const float* __restrict__ in,
                                                   const float* __restrict__ W,
                                                   const float* __restrict__ b,
                                                   float* __restrict__ out, int n) {
    __shared__ float sW[K * EMB];
    for (int i = threadIdx.x; i < K * EMB; i += blockDim.x) sW[i] = W[i];
    __syncthreads();
    int wave = blockIdx.x * (blockDim.x >> 6) + (threadIdx.x >> 6);
    int lane = threadIdx.x & 63;
    if (wave >= n) return;
    float v = (lane < K) ? in[wave * K + lane] : 0.0f;
    float acc = b[lane];
#pragma unroll
    for (int k = 0; k < K; ++k) {
        float hk = __shfl(v, k, 64);
        acc = fmaf(hk, sW[k * EMB + lane], acc);
    }
    out[wave * EMB + lane] = tanhf(acc);
}

// ---------------------------------------------------------------------------
// Fused pooling (segment max + mean) + output GEMV: one block (4 waves) per graph
// ---------------------------------------------------------------------------

__global__ __launch_bounds__(256) void pool_kernel(const float* __restrict__ h,
                                                   const int* __restrict__ gstart,
                                                   const float* __restrict__ Wout,
                                                   const float* __restrict__ bout,
                                                   float* __restrict__ out, int ng) {
    __shared__ float smx[4][EMB];
    __shared__ float ssm[4][EMB];
    int g = blockIdx.x;
    if (g >= ng) return;
    int w = threadIdx.x >> 6, lane = threadIdx.x & 63;
    int beg = gstart[g], end = gstart[g + 1];
    float mx = -3.0e38f, sm = 0.0f;
    for (int i = beg + w; i < end; i += 4) {
        float v = h[i * EMB + lane];
        mx = fmaxf(mx, v);
        sm += v;
    }
    smx[w][lane] = mx;
    ssm[w][lane] = sm;
    __syncthreads();
    if (w == 0) {
        mx = fmaxf(fmaxf(smx[0][lane], smx[1][lane]), fmaxf(smx[2][lane], smx[3][lane]));
        sm = ssm[0][lane] + ssm[1][lane] + ssm[2][lane] + ssm[3][lane];
        float mean = sm / (float)(end - beg);
        float r = mx * Wout[lane] + mean * Wout[EMB + lane];
#pragma unroll
        for (int off = 32; off; off >>= 1) r += __shfl_down(r, off, 64);
        if (lane == 0) out[g] = r + bout[0];
    }
}

// ---------------------------------------------------------------------------

extern "C" void kernel_launch(void* const* d_in, const int* in_sizes, int n_in,
                              void* d_out, int out_size, void* d_ws, size_t ws_size,
                              hipStream_t stream) {
    const float* x     = (const float*)d_in[0];
    const int*   ei    = (const int*)d_in[1];
    const int*   batch = (const int*)d_in[2];
    const float* W0 = (const float*)d_in[3];
    const float* b0 = (const float*)d_in[4];
    const float* W1 = (const float*)d_in[5];
    const float* b1 = (const float*)d_in[6];
    const float* W2 = (const float*)d_in[7];
    const float* b2 = (const float*)d_in[8];
    const float* W3 = (const float*)d_in[9];
    const float* b3 = (const float*)d_in[10];
    const float* Wout = (const float*)d_in[11];
    const float* bout = (const float*)d_in[12];
    float* out = (float*)d_out;

    // workspace layout (~36.4 MB)
    char* ws = (char*)d_ws;
    float* h_buf = (float*)ws;  ws += (size_t)N_NODES * EMB * 4;
    float* a_buf = (float*)ws;  ws += (size_t)N_NODES * EMB * 4;
    int2*  csr   = (int2*)ws;   ws += (size_t)N_EDGES * 8;
    int*   cnt   = (int*)ws;    ws += (size_t)N_NODES * 4;
    int*   fill  = (int*)ws;    ws += (size_t)N_NODES * 4;   // contiguous after cnt
    int*   rowp  = (int*)ws;    ws += (size_t)(N_NODES + 1) * 4;
    float* dinv  = (float*)ws;  ws += (size_t)N_NODES * 4;
    float* selfn = (float*)ws;  ws += (size_t)N_NODES * 4;
    int*   gstart= (int*)ws;    ws += (size_t)(N_GRAPHS + 1) * 4;
    int*   bsum  = (int*)ws;    ws += (size_t)SCAN_NB * 4;

    const int* srcp = ei;
    const int* dstp = ei + N_EDGES;

    // zero cnt+fill (contiguous; ws is re-poisoned 0xAA before every call)
    hipMemsetAsync(cnt, 0, (size_t)2 * N_NODES * 4, stream);

    int ebl = (N_EDGES + 255) / 256;
    int nbl = (N_NODES + 255) / 256;
    count_kernel<<<ebl, 256, 0, stream>>>(dstp, cnt, N_EDGES);
    blocksum_kernel<<<SCAN_NB, 256, 0, stream>>>(cnt, bsum, dinv, selfn, N_NODES);
    scanfill_kernel<<<SCAN_NB, 256, 0, stream>>>(cnt, bsum, rowp, N_NODES);
    fill_kernel<<<ebl, 256, 0, stream>>>(srcp, dstp, dinv, rowp, fill, csr, N_EDGES);
    boundary_kernel<<<nbl, 256, 0, stream>>>(batch, gstart, N_NODES, N_GRAPHS);

    int wbl = (N_NODES + 3) / 4;  // 4 waves (nodes) per 256-thread block

    // layer 0: aggregate 9-dim x, then 9->64 GEMV (+bias+tanh)
    agg9_kernel<<<wbl, 256, 0, stream>>>(x, csr, rowp, selfn, a_buf, N_NODES);
    gemv_kernel<N_FEAT><<<wbl, 256, 0, stream>>>(a_buf, W0, b0, h_buf, N_NODES);

    // layers 1..3: aggregate 64-dim h, then 64->64 GEMV (+bias+tanh)
    agg64_kernel<<<wbl, 256, 0, stream>>>(h_buf, csr, rowp, selfn, a_buf, N_NODES);
    gemv_kernel<EMB><<<wbl, 256, 0, stream>>>(a_buf, W1, b1, h_buf, N_NODES);
    agg64_kernel<<<wbl, 256, 0, stream>>>(h_buf, csr, rowp, selfn, a_buf, N_NODES);
    gemv_kernel<EMB><<<wbl, 256, 0, stream>>>(a_buf, W2, b2, h_buf, N_NODES);
    agg64_kernel<<<wbl, 256, 0, stream>>>(h_buf, csr, rowp, selfn, a_buf, N_NODES);
    gemv_kernel<EMB><<<wbl, 256, 0, stream>>>(a_buf, W3, b3, h_buf, N_NODES);

    pool_kernel<<<N_GRAPHS, 256, 0, stream>>>(h_buf, gstart, Wout, bout, out, N_GRAPHS);
}

// Round 5
// 406.987 us; speedup vs baseline: 1.5847x; 1.3954x over previous
//
#include <hip/hip_runtime.h>

#define N_NODES  50000
#define N_EDGES  1200000
#define N_GRAPHS 1024
#define N_FEAT   9
#define EMB      64
#define SCAN_NB  ((N_NODES + 255) / 256)   // 196 blocks

// ---------------------------------------------------------------------------
// CSR build. Trick: g = dinv*h prescale makes edge weights unnecessary:
//   agg_i = dinv_i * ( g_i + sum_{e:(src->i)} g[src_e] )   (== Â h + self term)
// so CSR stores ONLY the 4-byte src index.
// ---------------------------------------------------------------------------

// rank[e] = arrival index of edge e among edges with same dst; cnt[d] = degree
__global__ __launch_bounds__(256) void rank_kernel(const int* __restrict__ dst,
                                                   int* __restrict__ cnt,
                                                   int* __restrict__ rank, int ne) {
    int i = blockIdx.x * blockDim.x + threadIdx.x;
    if (i < ne) rank[i] = atomicAdd(&cnt[dst[i]], 1);
}

// per-block sums of cnt (for scan) + dinv + layer-0 prescale g0 = dinv * x
__global__ __launch_bounds__(256) void blocksum_kernel(const int* __restrict__ cnt,
                                                       const float* __restrict__ x,
                                                       int* __restrict__ bsum,
                                                       float* __restrict__ dinv,
                                                       float* __restrict__ g0,
                                                       int n) {
    __shared__ int sw[4];
    int t = threadIdx.x;
    int i = blockIdx.x * 256 + t;
    int v = (i < n) ? cnt[i] : 0;
    if (i < n) {
        float d = (float)v + 1.0f;       // degree with self-loop
        float dv = rsqrtf(d);
        dinv[i] = dv;
#pragma unroll
        for (int f = 0; f < N_FEAT; ++f)
            g0[i * N_FEAT + f] = dv * x[i * N_FEAT + f];
    }
    int r = v;
#pragma unroll
    for (int off = 32; off; off >>= 1) r += __shfl_down(r, off, 64);
    if ((t & 63) == 0) sw[t >> 6] = r;
    __syncthreads();
    if (t == 0) bsum[blockIdx.x] = sw[0] + sw[1] + sw[2] + sw[3];
}

// block prefix from bsum + block-local exclusive scan -> rowp
__global__ __launch_bounds__(256) void scanfill_kernel(const int* __restrict__ cnt,
                                                       const int* __restrict__ bsum,
                                                       int* __restrict__ rowp, int n) {
    __shared__ int sw[4];
    __shared__ int s_off;
    __shared__ int lds[256];
    int t = threadIdx.x;
    int p = (t < blockIdx.x) ? bsum[t] : 0;
#pragma unroll
    for (int off = 32; off; off >>= 1) p += __shfl_down(p, off, 64);
    if ((t & 63) == 0) sw[t >> 6] = p;
    __syncthreads();
    if (t == 0) s_off = sw[0] + sw[1] + sw[2] + sw[3];
    int i = blockIdx.x * 256 + t;
    int v = (i < n) ? cnt[i] : 0;
    lds[t] = v;
    __syncthreads();
    for (int off = 1; off < 256; off <<= 1) {
        int u = (t >= off) ? lds[t - off] : 0;
        __syncthreads();
        lds[t] += u;
        __syncthreads();
    }
    if (i < n) rowp[i] = s_off + lds[t] - v;   // exclusive
    if (i == 0) rowp[n] = N_EDGES;
}

// pure scatter: csr[rowp[d] + rank[e]] = src[e]
__global__ __launch_bounds__(256) void fill2_kernel(const int* __restrict__ src,
                                                    const int* __restrict__ dst,
                                                    const int* __restrict__ rank,
                                                    const int* __restrict__ rowp,
                                                    int* __restrict__ csr, int ne) {
    int i = blockIdx.x * blockDim.x + threadIdx.x;
    if (i >= ne) return;
    csr[rowp[dst[i]] + rank[i]] = src[i];
}

__global__ __launch_bounds__(256) void boundary_kernel(const int* __restrict__ batch,
                                                       int* __restrict__ gstart,
                                                       int n, int ngraphs) {
    int i = blockIdx.x * blockDim.x + threadIdx.x;
    if (i >= n) return;
    int b = batch[i];
    if (i == 0 || batch[i - 1] != b) gstart[b] = i;
    if (i == 0) gstart[ngraphs] = n;
}

// ---------------------------------------------------------------------------
// Layer-0 aggregation (9-dim): a[i] = dinv_i * (g0[i] + sum_e g0[src_e])
// wave per node; lane = 9*slot + feat; 7 edges per iteration
// ---------------------------------------------------------------------------

__global__ __launch_bounds__(256) void agg9_kernel(const float* __restrict__ g0,
                                                   const int* __restrict__ csr,
                                                   const int* __restrict__ rowp,
                                                   const float* __restrict__ dinv,
                                                   float* __restrict__ a, int n) {
    int wave = blockIdx.x * (blockDim.x >> 6) + (threadIdx.x >> 6);
    int lane = threadIdx.x & 63;
    if (wave >= n) return;
    int beg = rowp[wave], end = rowp[wave + 1];
    int slot = lane / 9;          // 0..7 (lane 63 -> slot 7, masked off)
    int f    = lane - slot * 9;   // 0..8
    float p = 0.0f;
    int e = beg;
    for (; e + 7 <= end; e += 7) {
        if (slot < 7) {
            int s = csr[e + slot];
            p += g0[s * N_FEAT + f];
        }
    }
    for (; e < end; ++e) {
        if (lane < N_FEAT) {
            int s = csr[e];
            p += g0[s * N_FEAT + lane];
        }
    }
    float tot = p;
#pragma unroll
    for (int s = 1; s < 7; ++s) {
        float t = __shfl(p, 9 * s + lane, 64);
        if (lane < N_FEAT) tot += t;
    }
    if (lane < N_FEAT)
        a[wave * N_FEAT + lane] = dinv[wave] * (tot + g0[wave * N_FEAT + lane]);
}

// ---------------------------------------------------------------------------
// 64-dim aggregation: a[i] = dinv_i * (g[i] + sum_e g[src_e])
// wave per node, lane per feature, 8x unrolled gathers for MLP
// ---------------------------------------------------------------------------

__global__ __launch_bounds__(256) void agg64_kernel(const float* __restrict__ g,
                                                    const int* __restrict__ csr,
                                                    const int* __restrict__ rowp,
                                                    const float* __restrict__ dinv,
                                                    float* __restrict__ a, int n) {
    int wave = blockIdx.x * (blockDim.x >> 6) + (threadIdx.x >> 6);
    int lane = threadIdx.x & 63;
    if (wave >= n) return;
    int beg = rowp[wave], end = rowp[wave + 1];
    float acc = g[(size_t)wave * EMB + lane];
    int e = beg;
    for (; e + 8 <= end; e += 8) {
        int s0 = csr[e],     s1 = csr[e + 1], s2 = csr[e + 2], s3 = csr[e + 3];
        int s4 = csr[e + 4], s5 = csr[e + 5], s6 = csr[e + 6], s7 = csr[e + 7];
        float v0 = g[(size_t)s0 * EMB + lane];
        float v1 = g[(size_t)s1 * EMB + lane];
        float v2 = g[(size_t)s2 * EMB + lane];
        float v3 = g[(size_t)s3 * EMB + lane];
        float v4 = g[(size_t)s4 * EMB + lane];
        float v5 = g[(size_t)s5 * EMB + lane];
        float v6 = g[(size_t)s6 * EMB + lane];
        float v7 = g[(size_t)s7 * EMB + lane];
        acc += ((v0 + v1) + (v2 + v3)) + ((v4 + v5) + (v6 + v7));
    }
    for (; e < end; ++e) {
        int s = csr[e];
        acc += g[(size_t)s * EMB + lane];
    }
    a[(size_t)wave * EMB + lane] = dinv[wave] * acc;
}

// ---------------------------------------------------------------------------
// Register-tiled GEMM + bias + tanh (+ optional dinv prescale of the output):
//   out[i,:] = tanh(in[i,:K] @ W + b) * (PRESCALE ? dinv[i] : 1)
// block = 64 nodes x 64 feats; thread = 4x4 tile; A,W staged in LDS.
// ---------------------------------------------------------------------------

template <int K, bool PRESCALE>
__global__ __launch_bounds__(256) void gemm_tile_kernel(const float* __restrict__ in,
                                                        const float* __restrict__ W,
                                                        const float* __restrict__ b,
                                                        const float* __restrict__ dinv,
                                                        float* __restrict__ out, int n) {
    __shared__ float sIn[64 * (K + 1)];
    __shared__ float sW[K * EMB];
    int tid = threadIdx.x;
    int base = blockIdx.x * 64;
    for (int i = tid; i < K * EMB; i += 256) sW[i] = W[i];
    for (int i = tid; i < 64 * K; i += 256) {
        int r = i / K, c = i - r * K;
        int node = base + r;
        sIn[r * (K + 1) + c] = (node < n) ? in[(size_t)node * K + c] : 0.0f;
    }
    __syncthreads();
    int tx = tid & 15, ty = tid >> 4;
    int f0 = tx * 4, n0 = ty * 4;
    float acc[4][4];
#pragma unroll
    for (int i = 0; i < 4; ++i)
#pragma unroll
        for (int j = 0; j < 4; ++j) acc[i][j] = b[f0 + j];
#pragma unroll 8
    for (int k = 0; k < K; ++k) {
        float a0 = sIn[(n0 + 0) * (K + 1) + k];
        float a1 = sIn[(n0 + 1) * (K + 1) + k];
        float a2 = sIn[(n0 + 2) * (K + 1) + k];
        float a3 = sIn[(n0 + 3) * (K + 1) + k];
        float4 wv = *(const float4*)&sW[k * EMB + f0];
        acc[0][0] = fmaf(a0, wv.x, acc[0][0]);
        acc[0][1] = fmaf(a0, wv.y, acc[0][1]);
        acc[0][2] = fmaf(a0, wv.z, acc[0][2]);
        acc[0][3] = fmaf(a0, wv.w, acc[0][3]);
        acc[1][0] = fmaf(a1, wv.x, acc[1][0]);
        acc[1][1] = fmaf(a1, wv.y, acc[1][1]);
        acc[1][2] = fmaf(a1, wv.z, acc[1][2]);
        acc[1][3] = fmaf(a1, wv.w, acc[1][3]);
        acc[2][0] = fmaf(a2, wv.x, acc[2][0]);
        acc[2][1] = fmaf(a2, wv.y, acc[2][1]);
        acc[2][2] = fmaf(a2, wv.z, acc[2][2]);
        acc[2][3] = fmaf(a2, wv.w, acc[2][3]);
        acc[3][0] = fmaf(a3, wv.x, acc[3][0]);
        acc[3][1] = fmaf(a3, wv.y, acc[3][1]);
        acc[3][2] = fmaf(a3, wv.z, acc[3][2]);
        acc[3][3] = fmaf(a3, wv.w, acc[3][3]);
    }
#pragma unroll
    for (int i = 0; i < 4; ++i) {
        int node = base + n0 + i;
        if (node < n) {
            float dv = PRESCALE ? dinv[node] : 1.0f;
            float4 o;
            o.x = tanhf(acc[i][0]) * dv;
            o.y = tanhf(acc[i][1]) * dv;
            o.z = tanhf(acc[i][2]) * dv;
            o.w = tanhf(acc[i][3]) * dv;
            *(float4*)&out[(size_t)node * EMB + f0] = o;
        }
    }
}

// ---------------------------------------------------------------------------
// Fused pooling (segment max + mean) + output GEMV: one block (4 waves) per graph
// ---------------------------------------------------------------------------

__global__ __launch_bounds__(256) void pool_kernel(const float* __restrict__ h,
                                                   const int* __restrict__ gstart,
                                                   const float* __restrict__ Wout,
                                                   const float* __restrict__ bout,
                                                   float* __restrict__ out, int ng) {
    __shared__ float smx[4][EMB];
    __shared__ float ssm[4][EMB];
    int g = blockIdx.x;
    if (g >= ng) return;
    int w = threadIdx.x >> 6, lane = threadIdx.x & 63;
    int beg = gstart[g], end = gstart[g + 1];
    float mx = -3.0e38f, sm = 0.0f;
    for (int i = beg + w; i < end; i += 4) {
        float v = h[(size_t)i * EMB + lane];
        mx = fmaxf(mx, v);
        sm += v;
    }
    smx[w][lane] = mx;
    ssm[w][lane] = sm;
    __syncthreads();
    if (w == 0) {
        mx = fmaxf(fmaxf(smx[0][lane], smx[1][lane]), fmaxf(smx[2][lane], smx[3][lane]));
        sm = ssm[0][lane] + ssm[1][lane] + ssm[2][lane] + ssm[3][lane];
        float mean = sm / (float)(end - beg);
        float r = mx * Wout[lane] + mean * Wout[EMB + lane];
#pragma unroll
        for (int off = 32; off; off >>= 1) r += __shfl_down(r, off, 64);
        if (lane == 0) out[g] = r + bout[0];
    }
}

// ---------------------------------------------------------------------------

extern "C" void kernel_launch(void* const* d_in, const int* in_sizes, int n_in,
                              void* d_out, int out_size, void* d_ws, size_t ws_size,
                              hipStream_t stream) {
    const float* x     = (const float*)d_in[0];
    const int*   ei    = (const int*)d_in[1];
    const int*   batch = (const int*)d_in[2];
    const float* W0 = (const float*)d_in[3];
    const float* b0 = (const float*)d_in[4];
    const float* W1 = (const float*)d_in[5];
    const float* b1 = (const float*)d_in[6];
    const float* W2 = (const float*)d_in[7];
    const float* b2 = (const float*)d_in[8];
    const float* W3 = (const float*)d_in[9];
    const float* b3 = (const float*)d_in[10];
    const float* Wout = (const float*)d_in[11];
    const float* bout = (const float*)d_in[12];
    float* out = (float*)d_out;

    // workspace layout (~36 MB)
    char* ws = (char*)d_ws;
    float* g_buf = (float*)ws;  ws += (size_t)N_NODES * EMB * 4;
    float* a_buf = (float*)ws;  ws += (size_t)N_NODES * EMB * 4;
    int*   csr   = (int*)ws;    ws += (size_t)N_EDGES * 4;
    int*   rank  = (int*)ws;    ws += (size_t)N_EDGES * 4;
    int*   cnt   = (int*)ws;    ws += (size_t)N_NODES * 4;
    int*   rowp  = (int*)ws;    ws += (size_t)(N_NODES + 1) * 4;
    float* dinv  = (float*)ws;  ws += (size_t)N_NODES * 4;
    int*   gstart= (int*)ws;    ws += (size_t)(N_GRAPHS + 1) * 4;
    int*   bsum  = (int*)ws;    ws += (size_t)SCAN_NB * 4;

    const int* srcp = ei;
    const int* dstp = ei + N_EDGES;

    hipMemsetAsync(cnt, 0, (size_t)N_NODES * 4, stream);

    int ebl = (N_EDGES + 255) / 256;
    int nbl = (N_NODES + 255) / 256;
    rank_kernel<<<ebl, 256, 0, stream>>>(dstp, cnt, rank, N_EDGES);
    blocksum_kernel<<<SCAN_NB, 256, 0, stream>>>(cnt, x, bsum, dinv, g_buf, N_NODES);
    scanfill_kernel<<<SCAN_NB, 256, 0, stream>>>(cnt, bsum, rowp, N_NODES);
    fill2_kernel<<<ebl, 256, 0, stream>>>(srcp, dstp, rank, rowp, csr, N_EDGES);
    boundary_kernel<<<nbl, 256, 0, stream>>>(batch, gstart, N_NODES, N_GRAPHS);

    int wbl = (N_NODES + 3) / 4;          // agg: 4 waves (nodes) per block
    int gbl = (N_NODES + 63) / 64;        // gemm: 64 nodes per block

    // layer 0
    agg9_kernel<<<wbl, 256, 0, stream>>>(g_buf, csr, rowp, dinv, a_buf, N_NODES);
    gemm_tile_kernel<N_FEAT, true><<<gbl, 256, 0, stream>>>(a_buf, W0, b0, dinv, g_buf, N_NODES);
    // layers 1..3
    agg64_kernel<<<wbl, 256, 0, stream>>>(g_buf, csr, rowp, dinv, a_buf, N_NODES);
    gemm_tile_kernel<EMB, true><<<gbl, 256, 0, stream>>>(a_buf, W1, b1, dinv, g_buf, N_NODES);
    agg64_kernel<<<wbl, 256, 0, stream>>>(g_buf, csr, rowp, dinv, a_buf, N_NODES);
    gemm_tile_kernel<EMB, true><<<gbl, 256, 0, stream>>>(a_buf, W2, b2, dinv, g_buf, N_NODES);
    agg64_kernel<<<wbl, 256, 0, stream>>>(g_buf, csr, rowp, dinv, a_buf, N_NODES);
    gemm_tile_kernel<EMB, false><<<gbl, 256, 0, stream>>>(a_buf, W3, b3, dinv, g_buf, N_NODES);

    pool_kernel<<<N_GRAPHS, 256, 0, stream>>>(g_buf, gstart, Wout, bout, out, N_GRAPHS);
}